// Round 10
// baseline (597.669 us; speedup 1.0000x reference)
//
#include <hip/hip_runtime.h>

typedef unsigned short u16;
typedef __bf16 bf16x8 __attribute__((ext_vector_type(8)));
typedef unsigned short u16x8 __attribute__((ext_vector_type(8)));
typedef float f32x4 __attribute__((ext_vector_type(4)));

// x: [16,4096,1024] f32, context: [16,77,768] f32
// Wq: [1024,1024], Wk/Wv: [768,1024], Wo: [1024,1024], bo: [1024]
// out: [16,4096,1024] f32
namespace {
constexpr int kB = 16;
constexpr int kHeads = 16, kDh = 64;
constexpr int kNcPadS = 80;
constexpr int kNcPadV = 96;

constexpr size_t oWqT = 0;                                         // [1024][1024] bf16 WqT[n][k]
constexpr size_t oWoT = oWqT + (size_t)1024 * 1024 * 2;
constexpr size_t oWkT = oWoT + (size_t)1024 * 1024 * 2;            // [1024][768]
constexpr size_t oWvT = oWkT + (size_t)1024 * 768 * 2;
constexpr size_t oCtx = oWvT + (size_t)1024 * 768 * 2;             // [1232][768]
constexpr size_t oKp  = oCtx + (size_t)1232 * 768 * 2;             // [16][16][80][64] (K/8)
constexpr size_t oVp  = oKp + (size_t)kB * kHeads * kNcPadS * kDh * 2; // [16][16][64][96] V^T
constexpr size_t oQ   = oVp + (size_t)kB * kHeads * kDh * kNcPadV * 2; // [65536][1024] bf16 (attn out)
} // namespace

__device__ __forceinline__ u16 f2b(float f) {
    __bf16 h = (__bf16)f;
    return __builtin_bit_cast(u16, h);
}
__device__ __forceinline__ bf16x8 ldfrag(const u16* p) {
    return __builtin_bit_cast(bf16x8, *reinterpret_cast<const u16x8*>(p));
}
__device__ __forceinline__ f32x4 mfma16(bf16x8 a, bf16x8 b, f32x4 c) {
    return __builtin_amdgcn_mfma_f32_16x16x32_bf16(a, b, c, 0, 0, 0);
}
__device__ __forceinline__ void gload16(const u16* g, u16* lds) {
    __builtin_amdgcn_global_load_lds(
        (const __attribute__((address_space(1))) void*)g,
        (__attribute__((address_space(3))) void*)lds, 16, 0, 0);
}
__device__ __forceinline__ u16x8 pk8(float4 a, float4 b) {
    u16x8 p = { f2b(a.x), f2b(a.y), f2b(a.z), f2b(a.w),
                f2b(b.x), f2b(b.y), f2b(b.z), f2b(b.w) };
    return p;
}

#define VMCNT(N) asm volatile("s_waitcnt vmcnt(" #N ")" ::: "memory")
#define LGKM0    asm volatile("s_waitcnt lgkmcnt(0)" ::: "memory")
#define BARRIER  do { __builtin_amdgcn_s_barrier(); asm volatile("" ::: "memory"); } while (0)

// ---- pair-packed LDS unit: 256 logical rows x 32 k bf16 = 16KB, phys [128 pairs][8 slots][16B].
// logical (R,k): pr=R>>1, slot = ((R&1)*4 + (k>>3)) ^ (pr&7). Verified conflict-free+correct (rounds 3-9).
__device__ __forceinline__ void stage_u(const u16* gp, u16* unit, int tid, int kt) {
#pragma unroll
    for (int i = 0; i < 2; ++i) {
        int g = tid + i * 512;
        int prs = g >> 3;
        int s0 = (g & 7) ^ (prs & 7);
        gload16(gp + (size_t)(prs * 2 + (s0 >> 2)) * 1024 + kt + (s0 & 3) * 8,
                unit + ((g >> 6) << 9));
    }
}
// pp16: same packing for a [16 rows][32 k] 1KB sub-unit (u16 offset)
__device__ __forceinline__ int pp16(int row16, int k32) {
    return (row16 >> 1) * 64 + (((((row16 & 1) << 2) | (k32 >> 3)) ^ ((row16 >> 1) & 7)) * 8) + (k32 & 7);
}

// ---------------- prep2: coalesced LDS-tiled weight transposes + ctx convert + K/V pad zero ----------------
__global__ __launch_bounds__(256) void prep2_kernel(
    const float* __restrict__ Wq, const float* __restrict__ Wk,
    const float* __restrict__ Wv, const float* __restrict__ Wo,
    const float* __restrict__ ctx, u16* __restrict__ ws) {
    __shared__ u16 tl[64][72];
    int b = blockIdx.x;
    int tid = threadIdx.x;
    if (b < 896) {
        const float* S; u16* D; int t, DC;
        if (b < 256)       { S = Wq; D = ws + oWqT / 2; t = b;       DC = 1024; }
        else if (b < 512)  { S = Wo; D = ws + oWoT / 2; t = b - 256; DC = 1024; }
        else if (b < 704)  { S = Wk; D = ws + oWkT / 2; t = b - 512; DC = 768;  }
        else               { S = Wv; D = ws + oWvT / 2; t = b - 704; DC = 768;  }
        int tk = t >> 4, tn = t & 15;
        int k0 = tk * 64, n0 = tn * 64;
#pragma unroll
        for (int i = 0; i < 4; ++i) {
            int r = (tid >> 4) + i * 16;
            float4 v = *reinterpret_cast<const float4*>(S + (size_t)(k0 + r) * 1024 + n0 + (tid & 15) * 4);
            u16 e0 = f2b(v.x), e1 = f2b(v.y), e2 = f2b(v.z), e3 = f2b(v.w);
            u16* p = &tl[r][(tid & 15) * 4];
            p[0] = e0; p[1] = e1; p[2] = e2; p[3] = e3;
        }
        __syncthreads();
#pragma unroll
        for (int i = 0; i < 2; ++i) {
            int n = (tid >> 3) + i * 32;
            u16x8 o;
#pragma unroll
            for (int j = 0; j < 8; ++j) o[j] = tl[(tid & 7) * 8 + j][n];
            *reinterpret_cast<u16x8*>(D + (size_t)(n0 + n) * DC + k0 + (tid & 7) * 8) = o;
        }
        return;
    }
    if (b < 896 + 462) {
        size_t i = (size_t)(b - 896) * 2048 + tid * 8;
        const float4* s = reinterpret_cast<const float4*>(ctx) + i / 4;
        float4 v0 = s[0], v1 = s[1];
        *reinterpret_cast<u16x8*>(ws + oCtx / 2 + i) = pk8(v0, v1);
        return;
    }
    size_t j = (size_t)(b - 896 - 462) * 2048 + tid * 8;
    u16x8 z = {0, 0, 0, 0, 0, 0, 0, 0};
    *reinterpret_cast<u16x8*>(ws + oKp / 2 + j) = z;
}

// ---------------- KV projection ----------------
__global__ __launch_bounds__(64) void kv_kernel(u16* __restrict__ ws) {
    const u16* ctxb = ws + oCtx / 2;
    const u16* WkT = ws + oWkT / 2;
    const u16* WvT = ws + oWvT / 2;
    u16* Kp = ws + oKp / 2;
    u16* Vp = ws + oVp / 2;
    int l = threadIdx.x;
    int mt = blockIdx.x >> 6;
    int nt = blockIdx.x & 63;
    int rowA = mt * 16 + (l & 15);
    int rowB = nt * 16 + (l & 15);
    int koff = (l >> 4) * 8;
    f32x4 accK = {0.f, 0.f, 0.f, 0.f}, accV = {0.f, 0.f, 0.f, 0.f};
    for (int k = 0; k < 768; k += 32) {
        bf16x8 a  = ldfrag(ctxb + rowA * 768 + k + koff);
        bf16x8 bk = ldfrag(WkT + rowB * 768 + k + koff);
        bf16x8 bv = ldfrag(WvT + rowB * 768 + k + koff);
        accK = mfma16(a, bk, accK);
        accV = mfma16(a, bv, accV);
    }
    int c = nt * 16 + (l & 15);
    int h = c >> 6, d = c & 63;
#pragma unroll
    for (int r = 0; r < 4; ++r) {
        int row = mt * 16 + (l >> 4) * 4 + r;
        int b = row / 77, j = row - b * 77;
        Kp[((size_t)(b * 16 + h) * kNcPadS + j) * kDh + d] = f2b(accK[r] * 0.125f);
        Vp[((size_t)(b * 16 + h) * kDh + d) * kNcPadV + j] = f2b(accV[r]);
    }
}

// ---------------- generic 4-phase GPHASE (verified rounds 6-9) ----------------
#define GPHASE(RLO, KS, READB, STAGE, VM) do {                                  \
    if (READB) { _Pragma("unroll") for (int c = 0; c < 4; ++c)                  \
        fb[c] = ldfrag(bU##KS + (wn * 4 + c) * 512 + rdoff); }                  \
    _Pragma("unroll") for (int r = 0; r < 4; ++r)                               \
        fa[r] = ldfrag(aU##KS + (wm * 8 + (RLO) + r) * 512 + rdoff);            \
    STAGE;                                                                      \
    BARRIER;                                                                    \
    __builtin_amdgcn_s_setprio(1);                                              \
    _Pragma("unroll") for (int r = 0; r < 4; ++r)                               \
        _Pragma("unroll") for (int c = 0; c < 4; ++c)                           \
            acc[(RLO) + r][c] = mfma16(fa[r], fb[c], acc[(RLO) + r][c]);        \
    __builtin_amdgcn_s_setprio(0);                                              \
    VM;                                                                         \
    BARRIER;                                                                    \
} while (0)

// outproj loop: both operands gload_lds (proven rounds 6-9)
#define GEMM_LOOP(aGp, bGp)                                                                          \
    stage_u(aGp, &sm[0][0][0][0], tid, 0);                                                           \
    stage_u(bGp, &sm[1][0][0][0], tid, 0);                                                           \
    stage_u(aGp, &sm[0][0][1][0], tid, 32);                                                          \
    stage_u(bGp, &sm[1][0][1][0], tid, 32);                                                          \
    stage_u(aGp, &sm[0][1][0][0], tid, 64);                                                          \
    stage_u(bGp, &sm[1][1][0][0], tid, 64);                                                          \
    VMCNT(8); BARRIER;                                                                               \
    for (int t = 0; t < 16; ++t) {                                                                   \
        const int d = t & 1, e = d ^ 1;                                                              \
        const u16* aU0 = &sm[0][d][0][0];                                                            \
        const u16* aU1 = &sm[0][d][1][0];                                                            \
        const u16* bU0 = &sm[1][d][0][0];                                                            \
        const u16* bU1 = &sm[1][d][1][0];                                                            \
        bf16x8 fa[4], fb[4];                                                                         \
        GPHASE(0, 0, true,  { if (t < 15) stage_u(aGp, &sm[0][e][1][0], tid, (t + 1) * 64 + 32); },  \
               {});                                                                                  \
        GPHASE(4, 0, false, { if (t < 15) stage_u(bGp, &sm[1][e][1][0], tid, (t + 1) * 64 + 32); },  \
               { if (t < 15) { VMCNT(8); } else { VMCNT(0); } });                                    \
        GPHASE(0, 1, true,  { if (t < 14) stage_u(aGp, &sm[0][d][0][0], tid, (t + 2) * 64); },       \
               {});                                                                                  \
        GPHASE(4, 1, false, { if (t < 14) stage_u(bGp, &sm[1][d][0][0], tid, (t + 2) * 64); },       \
               { if (t < 14) { VMCNT(8); } else if (t == 14) { VMCNT(4); } });                       \
    }

// ---------------- qproj+attn fused: A = fp32 x reg-staged (xconv eliminated), B = gload_lds ----------------
// vmcnt FIFO (per thread, per tile t): ph0 issue 8xA(t+2) f4; ph1 issue 2xB(t+1)h1 then VMCNT(12)
// [retires B(t)h1 AND A(t+1)]; ph2 write A(t+1)h0 (+lgkm0); ph3 issue 2xB(t+2)h0, write A(t+1)h1,
// VMCNT(12) [retires B(t+1)h0]. Steady invariant after ph3: {8A(t+2), 2B(t+1)h1, 2B(t+2)h0} = 12.
// Tail: t=14 -> VMCNT(4)/VMCNT(2); t=15 -> VMCNT(0)/none. Derived twice; A-flight = 2 tiles.
#define QISS(SET, KT) do {                                                                \
    SET##0 = *reinterpret_cast<const float4*>(aF0 + (KT));                                \
    SET##1 = *reinterpret_cast<const float4*>(aF0 + (KT) + 4);                            \
    SET##2 = *reinterpret_cast<const float4*>(aF1 + (KT));                                \
    SET##3 = *reinterpret_cast<const float4*>(aF1 + (KT) + 4);                            \
    SET##4 = *reinterpret_cast<const float4*>(aF0 + (KT) + 32);                           \
    SET##5 = *reinterpret_cast<const float4*>(aF0 + (KT) + 36);                           \
    SET##6 = *reinterpret_cast<const float4*>(aF1 + (KT) + 32);                           \
    SET##7 = *reinterpret_cast<const float4*>(aF1 + (KT) + 36);                           \
} while (0)
#define QWRT0(SET, BUF) do {                                                              \
    u16* u_ = &sm[0][BUF][0][0];                                                          \
    *reinterpret_cast<u16x8*>(u_ + tid * 8) = pk8(SET##0, SET##1);                        \
    *reinterpret_cast<u16x8*>(u_ + (tid + 512) * 8) = pk8(SET##2, SET##3);                \
} while (0)
#define QWRT1(SET, BUF) do {                                                              \
    u16* u_ = &sm[0][BUF][1][0];                                                          \
    *reinterpret_cast<u16x8*>(u_ + tid * 8) = pk8(SET##4, SET##5);                        \
    *reinterpret_cast<u16x8*>(u_ + (tid + 512) * 8) = pk8(SET##6, SET##7);                \
} while (0)

#define QTILE(T, CUR, NXT) do {                                                           \
    const int t_ = (T);                                                                   \
    const int d = t_ & 1, e = d ^ 1;                                                      \
    const u16* aU0 = &sm[0][d][0][0];                                                     \
    const u16* aU1 = &sm[0][d][1][0];                                                     \
    const u16* bU0 = &sm[1][d][0][0];                                                     \
    const u16* bU1 = &sm[1][d][1][0];                                                     \
    bf16x8 fa[4], fb[4];                                                                  \
    GPHASE(0, 0, true,  { if (t_ + 2 <= 15) QISS(NXT, (t_ + 2) * 64); }, {});             \
    GPHASE(4, 0, false, { if (t_ + 1 <= 15) stage_u(bG, &sm[1][e][1][0], tid, (t_ + 1) * 64 + 32); }, \
           { if (t_ <= 13) { VMCNT(12); } else if (t_ == 14) { VMCNT(4); } else { VMCNT(0); } });     \
    GPHASE(0, 1, true,  {}, { if (t_ + 1 <= 15) { QWRT0(CUR, e); LGKM0; } });             \
    GPHASE(4, 1, false, { if (t_ + 2 <= 15) stage_u(bG, &sm[1][d][0][0], tid, (t_ + 2) * 64); },      \
           { if (t_ + 1 <= 15) { QWRT1(CUR, e); LGKM0; }                                  \
             if (t_ <= 13) { VMCNT(12); } else if (t_ == 14) { VMCNT(2); } });            \
} while (0)

__global__ __launch_bounds__(512) void qproj_attn_kernel(const float* __restrict__ x, u16* __restrict__ ws) {
    __shared__ u16 sm[2][2][2][8192];   // 128 KiB; sm[0]=A (ds_write target), sm[1]=B (gload)
    __shared__ u16 Pb[8][1536];         // per-wave P tile (24 KiB)
    const u16* WqT = ws + oWqT / 2;
    u16* qb = ws + oQ / 2;
    int tid = threadIdx.x;
    int lane = tid & 63;
    int w = tid >> 6, wm = w >> 2, wn = w & 3;
    int lr = lane & 15, lr2 = lr >> 1;
    const int rdoff = lr2 * 64 + (((((lane & 1) << 2) | (lane >> 4))) ^ lr2) * 8;
    int bid = blockIdx.x;
    int wg = (bid & 7) * 128 + (bid >> 3);   // XCD swizzle (1024 % 8 == 0, bijective)
    int bm = wg >> 2, bn = wg & 3;

    // A-source addressing (pair-packed granules tid, tid+512; granule tid+512 = same s0, row+128)
    int prs = tid >> 3;
    int s0 = (tid & 7) ^ (prs & 7);
    const float* aF0 = x + (size_t)(bm * 256 + prs * 2 + (s0 >> 2)) * 1024 + (s0 & 3) * 8;
    const float* aF1 = aF0 + (size_t)128 * 1024;
    const u16* bG = WqT + (size_t)(bn * 256) * 1024;

    f32x4 acc[8][4] = {};
    float4 Aq0, Aq1, Aq2, Aq3, Aq4, Aq5, Aq6, Aq7;   // set A (odd-parity A-tiles)
    float4 Bq0, Bq1, Bq2, Bq3, Bq4, Bq5, Bq6, Bq7;   // set B (even-parity)

    // prologue: A(0)->setB, B(0)h0h1, A(1)->setA, B(1)h0; write A(0); drain B(0); fence.
    QISS(Bq, 0);
    stage_u(bG, &sm[1][0][0][0], tid, 0);
    stage_u(bG, &sm[1][0][1][0], tid, 32);
    QISS(Aq, 64);
    stage_u(bG, &sm[1][1][0][0], tid, 64);
    VMCNT(14);                 // A(0) landed (remaining: 4 B(0) + 8 A(1) + 2 B(1)h0)
    QWRT0(Bq, 0); QWRT1(Bq, 0);
    LGKM0;
    VMCNT(10);                 // B(0) landed (remaining: 8 A(1) + 2 B(1)h0)
    BARRIER;

    for (int sp = 0; sp < 8; ++sp) {
        QTILE(2 * sp, Aq, Bq);       // even tile: CUR=A holds A(t+1); NXT=B receives A(t+2)
        QTILE(2 * sp + 1, Bq, Aq);
    }

    // ---- fused attention epilogue (verified rounds 8/9) ----
    u16* smf = &sm[0][0][0][0];
    u16* qw = smf + (size_t)w * 8192;   // wave-private 16 KB: 16 units [16 rows][32 k] pp16
    u16* Pw = &Pb[w][0];
    int g = lane >> 4, g8 = g * 8;

#pragma unroll
    for (int r = 0; r < 8; ++r)
#pragma unroll
        for (int c = 0; c < 4; ++c) {
            int dd = c * 16 + lr;
            int unit = r * 2 + (dd >> 5);
            int k32 = dd & 31;
#pragma unroll
            for (int reg = 0; reg < 4; ++reg)
                qw[unit * 512 + pp16(g * 4 + reg, k32)] = f2b(acc[r][c][reg]);
        }
    {
        u16x8 z = {0, 0, 0, 0, 0, 0, 0, 0};
        *reinterpret_cast<u16x8*>(Pw + 2 * 512 + lane * 8) = z;
    }
    int b = bm >> 4;
    int h = bn * 4 + wn;
    const u16* Kh = ws + oKp / 2 + (size_t)(b * 16 + h) * kNcPadS * kDh;
    const u16* Vh = ws + oVp / 2 + (size_t)(b * 16 + h) * kDh * kNcPadV;
    bf16x8 kf[5][2], vf[3][4];
#pragma unroll
    for (int nt = 0; nt < 5; ++nt)
#pragma unroll
        for (int kc = 0; kc < 2; ++kc)
            kf[nt][kc] = ldfrag(Kh + (nt * 16 + lr) * 64 + kc * 32 + g8);
#pragma unroll
    for (int kti = 0; kti < 3; ++kti)
#pragma unroll
        for (int nt = 0; nt < 4; ++nt)
            vf[kti][nt] = ldfrag(Vh + (nt * 16 + lr) * kNcPadV + kti * 32 + g8);
    u16x8 bmask[3];
#pragma unroll
    for (int kti = 0; kti < 3; ++kti)
#pragma unroll
        for (int j = 0; j < 8; ++j)
            bmask[kti][j] = (kti * 32 + g8 + j < 77) ? (u16)0x3F80 : (u16)0;

#pragma unroll 1
    for (int rb = 0; rb < 8; ++rb) {
        f32x4 s[5] = {};
#pragma unroll
        for (int kc = 0; kc < 2; ++kc) {
            bf16x8 a = ldfrag(qw + (rb * 2 + kc) * 512 + rdoff);
#pragma unroll
            for (int nt = 0; nt < 5; ++nt) s[nt] = mfma16(a, kf[nt][kc], s[nt]);
        }
#pragma unroll
        for (int nt = 0; nt < 5; ++nt)
#pragma unroll
            for (int reg = 0; reg < 4; ++reg) {
                int j = nt * 16 + lr;
                Pw[(j >> 5) * 512 + pp16(g * 4 + reg, j & 31)] = f2b(__expf(s[nt][reg]));
            }
        f32x4 o[4] = {};
        f32x4 msum = {0.f, 0.f, 0.f, 0.f};
#pragma unroll
        for (int kti = 0; kti < 3; ++kti) {
            bf16x8 a = ldfrag(Pw + kti * 512 + rdoff);
#pragma unroll
            for (int nt = 0; nt < 4; ++nt) o[nt] = mfma16(a, vf[kti][nt], o[nt]);
            msum = mfma16(a, __builtin_bit_cast(bf16x8, bmask[kti]), msum);
        }
#pragma unroll
        for (int reg = 0; reg < 4; ++reg) {
            float rinv = 1.f / msum[reg];
            int row = bm * 256 + wm * 128 + rb * 16 + g * 4 + reg;
#pragma unroll
            for (int nt = 0; nt < 4; ++nt)
                qb[(size_t)row * 1024 + h * 64 + nt * 16 + lr] = f2b(o[nt][reg] * rinv);
        }
    }
}

// ---------------- outproj: out = attn @ WoT + bo ----------------
__global__ __launch_bounds__(512) void outproj_kernel(u16* __restrict__ ws, const float* __restrict__ bo,
                                                      float* __restrict__ out) {
    __shared__ u16 sm[2][2][2][8192];
    const u16* qb = ws + oQ / 2;
    const u16* WoT = ws + oWoT / 2;
    int tid = threadIdx.x;
    int lane = tid & 63;
    int w = tid >> 6, wm = w >> 2, wn = w & 3;
    int lr = lane & 15, lr2 = lr >> 1;
    const int rdoff = lr2 * 64 + (((((lane & 1) << 2) | (lane >> 4))) ^ lr2) * 8;
    int bid = blockIdx.x;
    int wg = (bid & 7) * 128 + (bid >> 3);
    int bm = wg >> 2, bn = wg & 3;

    const u16* aG = qb + (size_t)(bm * 256) * 1024;
    const u16* bG = WoT + (size_t)(bn * 256) * 1024;

    f32x4 acc[8][4] = {};
    GEMM_LOOP(aG, bG);

#pragma unroll
    for (int c = 0; c < 4; ++c) {
        int col = bn * 256 + wn * 64 + c * 16 + lr;
        float bias = bo[col];
#pragma unroll
        for (int r = 0; r < 8; ++r)
#pragma unroll
            for (int reg = 0; reg < 4; ++reg) {
                int row = bm * 256 + wm * 128 + r * 16 + (lane >> 4) * 4 + reg;
                out[(size_t)row * 1024 + col] = acc[r][c][reg] + bias;
            }
    }
}

extern "C" void kernel_launch(void* const* d_in, const int* in_sizes, int n_in,
                              void* d_out, int out_size, void* d_ws, size_t ws_size,
                              hipStream_t stream) {
    const float* x   = (const float*)d_in[0];
    const float* ctx = (const float*)d_in[1];
    const float* Wq  = (const float*)d_in[2];
    const float* Wk  = (const float*)d_in[3];
    const float* Wv  = (const float*)d_in[4];
    const float* Wo  = (const float*)d_in[5];
    const float* bo  = (const float*)d_in[6];
    float* out = (float*)d_out;
    u16* ws = (u16*)d_ws;
    (void)in_sizes; (void)n_in; (void)out_size; (void)ws_size;

    prep2_kernel<<<896 + 462 + 1408, 256, 0, stream>>>(Wq, Wk, Wv, Wo, ctx, ws);
    kv_kernel<<<77 * 64, 64, 0, stream>>>(ws);
    qproj_attn_kernel<<<1024, 512, 0, stream>>>(x, ws);
    outproj_kernel<<<1024, 512, 0, stream>>>(ws, bo, out);
}

// Round 11
// 501.246 us; speedup vs baseline: 1.1924x; 1.1924x over previous
//
#include <hip/hip_runtime.h>

typedef unsigned short u16;
typedef __bf16 bf16x8 __attribute__((ext_vector_type(8)));
typedef unsigned short u16x8 __attribute__((ext_vector_type(8)));
typedef float f32x4 __attribute__((ext_vector_type(4)));

// x: [16,4096,1024] f32, context: [16,77,768] f32
// Wq: [1024,1024], Wk/Wv: [768,1024], Wo: [1024,1024], bo: [1024]
// out: [16,4096,1024] f32
namespace {
constexpr int kB = 16;
constexpr int kHeads = 16, kDh = 64;
constexpr int kNcPadS = 80;
constexpr int kNcPadV = 96;

constexpr size_t oWqT = 0;                                         // [1024][1024] bf16 WqT[n][k]
constexpr size_t oWoT = oWqT + (size_t)1024 * 1024 * 2;
constexpr size_t oWkT = oWoT + (size_t)1024 * 1024 * 2;            // [1024][768]
constexpr size_t oWvT = oWkT + (size_t)1024 * 768 * 2;
constexpr size_t oCtx = oWvT + (size_t)1024 * 768 * 2;             // [1232][768]
constexpr size_t oKp  = oCtx + (size_t)1232 * 768 * 2;             // [16][16][80][64] (K/8)
constexpr size_t oVp  = oKp + (size_t)kB * kHeads * kNcPadS * kDh * 2; // [16][16][64][96] V^T
constexpr size_t oQ   = oVp + (size_t)kB * kHeads * kDh * kNcPadV * 2; // [65536][1024] bf16 (attn out)
constexpr int kXBlocks = 32768;   // x-convert blocks (16*4096*1024 / 8 / 256)
} // namespace

__device__ __forceinline__ u16 f2b(float f) {
    __bf16 h = (__bf16)f;
    return __builtin_bit_cast(u16, h);
}
__device__ __forceinline__ bf16x8 ldfrag(const u16* p) {
    return __builtin_bit_cast(bf16x8, *reinterpret_cast<const u16x8*>(p));
}
__device__ __forceinline__ f32x4 mfma16(bf16x8 a, bf16x8 b, f32x4 c) {
    return __builtin_amdgcn_mfma_f32_16x16x32_bf16(a, b, c, 0, 0, 0);
}
__device__ __forceinline__ void gload16(const u16* g, u16* lds) {
    __builtin_amdgcn_global_load_lds(
        (const __attribute__((address_space(1))) void*)g,
        (__attribute__((address_space(3))) void*)lds, 16, 0, 0);
}
__device__ __forceinline__ u16x8 pk8(float4 a, float4 b) {
    u16x8 p = { f2b(a.x), f2b(a.y), f2b(a.z), f2b(a.w),
                f2b(b.x), f2b(b.y), f2b(b.z), f2b(b.w) };
    return p;
}

#define VMCNT(N) asm volatile("s_waitcnt vmcnt(" #N ")" ::: "memory")
#define BARRIER  do { __builtin_amdgcn_s_barrier(); asm volatile("" ::: "memory"); } while (0)

// ---- pair-packed LDS unit: 256 logical rows x 32 k bf16 = 16KB, phys [128 pairs][8 slots][16B].
// logical (R,k): pr=R>>1, slot = ((R&1)*4 + (k>>3)) ^ (pr&7). Verified conflict-free+correct (rounds 3-9).
__device__ __forceinline__ void stage_u(const u16* gp, u16* unit, int tid, int kt) {
#pragma unroll
    for (int i = 0; i < 2; ++i) {
        int g = tid + i * 512;
        int prs = g >> 3;
        int s0 = (g & 7) ^ (prs & 7);
        gload16(gp + (size_t)(prs * 2 + (s0 >> 2)) * 1024 + kt + (s0 & 3) * 8,
                unit + ((g >> 6) << 9));
    }
}
// pp16: same packing for a [16 rows][32 k] 1KB sub-unit (u16 offset)
__device__ __forceinline__ int pp16(int row16, int k32) {
    return (row16 >> 1) * 64 + (((((row16 & 1) << 2) | (k32 >> 3)) ^ ((row16 >> 1) & 7)) * 8) + (k32 & 7);
}

// ---------------- prep: x->bf16 (bulk, runs concurrently with the rest) + weight transposes +
// ctx convert + K/V pad zero — single grid so the small prep work hides under xconv's HBM stream ----
__global__ __launch_bounds__(256) void prep2_kernel(
    const float* __restrict__ Wq, const float* __restrict__ Wk,
    const float* __restrict__ Wv, const float* __restrict__ Wo,
    const float* __restrict__ ctx, const float* __restrict__ x,
    u16* __restrict__ ws, u16* __restrict__ xb) {
    __shared__ u16 tl[64][72];
    int b = blockIdx.x;
    int tid = threadIdx.x;
    if (b < kXBlocks) {   // x fp32 -> bf16 into d_out scratch (8 elems/thread)
        size_t i = (size_t)b * 256 + tid;
        const float4* s = reinterpret_cast<const float4*>(x) + 2 * i;
        float4 v0 = s[0], v1 = s[1];
        *reinterpret_cast<u16x8*>(xb + 8 * i) = pk8(v0, v1);
        return;
    }
    b -= kXBlocks;
    if (b < 896) {
        const float* S; u16* D; int t, DC;
        if (b < 256)       { S = Wq; D = ws + oWqT / 2; t = b;       DC = 1024; }
        else if (b < 512)  { S = Wo; D = ws + oWoT / 2; t = b - 256; DC = 1024; }
        else if (b < 704)  { S = Wk; D = ws + oWkT / 2; t = b - 512; DC = 768;  }
        else               { S = Wv; D = ws + oWvT / 2; t = b - 704; DC = 768;  }
        int tk = t >> 4, tn = t & 15;
        int k0 = tk * 64, n0 = tn * 64;
#pragma unroll
        for (int i = 0; i < 4; ++i) {
            int r = (tid >> 4) + i * 16;
            float4 v = *reinterpret_cast<const float4*>(S + (size_t)(k0 + r) * 1024 + n0 + (tid & 15) * 4);
            u16 e0 = f2b(v.x), e1 = f2b(v.y), e2 = f2b(v.z), e3 = f2b(v.w);
            u16* p = &tl[r][(tid & 15) * 4];
            p[0] = e0; p[1] = e1; p[2] = e2; p[3] = e3;
        }
        __syncthreads();
#pragma unroll
        for (int i = 0; i < 2; ++i) {
            int n = (tid >> 3) + i * 32;
            u16x8 o;
#pragma unroll
            for (int j = 0; j < 8; ++j) o[j] = tl[(tid & 7) * 8 + j][n];
            *reinterpret_cast<u16x8*>(D + (size_t)(n0 + n) * DC + k0 + (tid & 7) * 8) = o;
        }
        return;
    }
    if (b < 896 + 462) {
        size_t i = (size_t)(b - 896) * 2048 + tid * 8;
        const float4* s = reinterpret_cast<const float4*>(ctx) + i / 4;
        float4 v0 = s[0], v1 = s[1];
        *reinterpret_cast<u16x8*>(ws + oCtx / 2 + i) = pk8(v0, v1);
        return;
    }
    size_t j = (size_t)(b - 896 - 462) * 2048 + tid * 8;
    u16x8 z = {0, 0, 0, 0, 0, 0, 0, 0};
    *reinterpret_cast<u16x8*>(ws + oKp / 2 + j) = z;
}

// ---------------- KV projection ----------------
__global__ __launch_bounds__(64) void kv_kernel(u16* __restrict__ ws) {
    const u16* ctxb = ws + oCtx / 2;
    const u16* WkT = ws + oWkT / 2;
    const u16* WvT = ws + oWvT / 2;
    u16* Kp = ws + oKp / 2;
    u16* Vp = ws + oVp / 2;
    int l = threadIdx.x;
    int mt = blockIdx.x >> 6;
    int nt = blockIdx.x & 63;
    int rowA = mt * 16 + (l & 15);
    int rowB = nt * 16 + (l & 15);
    int koff = (l >> 4) * 8;
    f32x4 accK = {0.f, 0.f, 0.f, 0.f}, accV = {0.f, 0.f, 0.f, 0.f};
    for (int k = 0; k < 768; k += 32) {
        bf16x8 a  = ldfrag(ctxb + rowA * 768 + k + koff);
        bf16x8 bk = ldfrag(WkT + rowB * 768 + k + koff);
        bf16x8 bv = ldfrag(WvT + rowB * 768 + k + koff);
        accK = mfma16(a, bk, accK);
        accV = mfma16(a, bv, accV);
    }
    int c = nt * 16 + (l & 15);
    int h = c >> 6, d = c & 63;
#pragma unroll
    for (int r = 0; r < 4; ++r) {
        int row = mt * 16 + (l >> 4) * 4 + r;
        int b = row / 77, j = row - b * 77;
        Kp[((size_t)(b * 16 + h) * kNcPadS + j) * kDh + d] = f2b(accK[r] * 0.125f);
        Vp[((size_t)(b * 16 + h) * kDh + d) * kNcPadV + j] = f2b(accV[r]);
    }
}

// ---------------- m201-style 4-phase K-tile GEMM schedule (verified rounds 6-9) ----------------
#define GPHASE(RLO, KS, READB, STAGE, VM) do {                                  \
    if (READB) { _Pragma("unroll") for (int c = 0; c < 4; ++c)                  \
        fb[c] = ldfrag(bU##KS + (wn * 4 + c) * 512 + rdoff); }                  \
    _Pragma("unroll") for (int r = 0; r < 4; ++r)                               \
        fa[r] = ldfrag(aU##KS + (wm * 8 + (RLO) + r) * 512 + rdoff);            \
    STAGE;                                                                      \
    BARRIER;                                                                    \
    __builtin_amdgcn_s_setprio(1);                                              \
    _Pragma("unroll") for (int r = 0; r < 4; ++r)                               \
        _Pragma("unroll") for (int c = 0; c < 4; ++c)                           \
            acc[(RLO) + r][c] = mfma16(fa[r], fb[c], acc[(RLO) + r][c]);        \
    __builtin_amdgcn_s_setprio(0);                                              \
    VM;                                                                         \
    BARRIER;                                                                    \
} while (0)

#define GEMM_LOOP(aGp, bGp)                                                                          \
    stage_u(aGp, &sm[0][0][0][0], tid, 0);                                                           \
    stage_u(bGp, &sm[1][0][0][0], tid, 0);                                                           \
    stage_u(aGp, &sm[0][0][1][0], tid, 32);                                                          \
    stage_u(bGp, &sm[1][0][1][0], tid, 32);                                                          \
    stage_u(aGp, &sm[0][1][0][0], tid, 64);                                                          \
    stage_u(bGp, &sm[1][1][0][0], tid, 64);                                                          \
    VMCNT(8); BARRIER;                                                                               \
    for (int t = 0; t < 16; ++t) {                                                                   \
        const int d = t & 1, e = d ^ 1;                                                              \
        const u16* aU0 = &sm[0][d][0][0];                                                            \
        const u16* aU1 = &sm[0][d][1][0];                                                            \
        const u16* bU0 = &sm[1][d][0][0];                                                            \
        const u16* bU1 = &sm[1][d][1][0];                                                            \
        bf16x8 fa[4], fb[4];                                                                         \
        GPHASE(0, 0, true,  { if (t < 15) stage_u(aGp, &sm[0][e][1][0], tid, (t + 1) * 64 + 32); },  \
               {});                                                                                  \
        GPHASE(4, 0, false, { if (t < 15) stage_u(bGp, &sm[1][e][1][0], tid, (t + 1) * 64 + 32); },  \
               { if (t < 15) { VMCNT(8); } else { VMCNT(0); } });                                    \
        GPHASE(0, 1, true,  { if (t < 14) stage_u(aGp, &sm[0][d][0][0], tid, (t + 2) * 64); },       \
               {});                                                                                  \
        GPHASE(4, 1, false, { if (t < 14) stage_u(bGp, &sm[1][d][0][0], tid, (t + 2) * 64); },       \
               { if (t < 14) { VMCNT(8); } else if (t == 14) { VMCNT(4); } });                       \
    }

// ---------------- qproj+attn fused: q = xb @ WqT, then per-wave attention, write attn-out ----------------
__global__ __launch_bounds__(512) void qproj_attn_kernel(const u16* __restrict__ xb, u16* __restrict__ ws) {
    __shared__ u16 sm[2][2][2][8192];   // 128 KiB GEMM buffers; reused as q store after the loop
    __shared__ u16 Pb[8][1536];         // per-wave P tile: 3 pp16 units of [16][32] (24 KiB)
    const u16* WqT = ws + oWqT / 2;
    u16* qb = ws + oQ / 2;
    int tid = threadIdx.x;
    int lane = tid & 63;
    int w = tid >> 6, wm = w >> 2, wn = w & 3;
    int lr = lane & 15, lr2 = lr >> 1;
    const int rdoff = lr2 * 64 + (((((lane & 1) << 2) | (lane >> 4))) ^ lr2) * 8;
    int bid = blockIdx.x;
    int wg = (bid & 7) * 128 + (bid >> 3);   // XCD swizzle (1024 % 8 == 0, bijective)
    int bm = wg >> 2, bn = wg & 3;

    const u16* aG = xb + (size_t)(bm * 256) * 1024;
    const u16* bG = WqT + (size_t)(bn * 256) * 1024;

    f32x4 acc[8][4] = {};
    GEMM_LOOP(aG, bG);

    // ---- fused attention epilogue (verified rounds 8/9) ----
    u16* smf = &sm[0][0][0][0];
    u16* qw = smf + (size_t)w * 8192;   // wave-private 16 KB: 16 units [16 rows][32 k] pp16
    u16* Pw = &Pb[w][0];
    int g = lane >> 4, g8 = g * 8;

    // write q tile bf16 to LDS (unit = r*2 + (d>>5); frees acc)
#pragma unroll
    for (int r = 0; r < 8; ++r)
#pragma unroll
        for (int c = 0; c < 4; ++c) {
            int dd = c * 16 + lr;
            int unit = r * 2 + (dd >> 5);
            int k32 = dd & 31;
#pragma unroll
            for (int reg = 0; reg < 4; ++reg)
                qw[unit * 512 + pp16(g * 4 + reg, k32)] = f2b(acc[r][c][reg]);
        }
    // zero P unit 2 (cols 64..95; 64..79 rewritten per row-block before each read)
    {
        u16x8 z = {0, 0, 0, 0, 0, 0, 0, 0};
        *reinterpret_cast<u16x8*>(Pw + 2 * 512 + lane * 8) = z;
    }
    // hoist K/V fragments from global (L2-resident; K pre-scaled by 1/8, pads zeroed)
    int b = bm >> 4;
    int h = bn * 4 + wn;
    const u16* Kh = ws + oKp / 2 + (size_t)(b * 16 + h) * kNcPadS * kDh;
    const u16* Vh = ws + oVp / 2 + (size_t)(b * 16 + h) * kDh * kNcPadV;
    bf16x8 kf[5][2], vf[3][4];
#pragma unroll
    for (int nt = 0; nt < 5; ++nt)
#pragma unroll
        for (int kc = 0; kc < 2; ++kc)
            kf[nt][kc] = ldfrag(Kh + (nt * 16 + lr) * 64 + kc * 32 + g8);
#pragma unroll
    for (int kti = 0; kti < 3; ++kti)
#pragma unroll
        for (int nt = 0; nt < 4; ++nt)
            vf[kti][nt] = ldfrag(Vh + (nt * 16 + lr) * kNcPadV + kti * 32 + g8);
    u16x8 bmask[3];
#pragma unroll
    for (int kti = 0; kti < 3; ++kti)
#pragma unroll
        for (int j = 0; j < 8; ++j)
            bmask[kti][j] = (kti * 32 + g8 + j < 77) ? (u16)0x3F80 : (u16)0;

#pragma unroll 1
    for (int rb = 0; rb < 8; ++rb) {
        // scores (no max-subtraction: s~N(0,1), softmax shift-invariant — verified rounds 7-9)
        f32x4 s[5] = {};
#pragma unroll
        for (int kc = 0; kc < 2; ++kc) {
            bf16x8 a = ldfrag(qw + (rb * 2 + kc) * 512 + rdoff);
#pragma unroll
            for (int nt = 0; nt < 5; ++nt) s[nt] = mfma16(a, kf[nt][kc], s[nt]);
        }
        // P = exp(s) -> wave-private pp16 tile
#pragma unroll
        for (int nt = 0; nt < 5; ++nt)
#pragma unroll
            for (int reg = 0; reg < 4; ++reg) {
                int j = nt * 16 + lr;
                Pw[(j >> 5) * 512 + pp16(g * 4 + reg, j & 31)] = f2b(__expf(s[nt][reg]));
            }
        // PV + masked-ones row-sum via MFMA (compiler inserts the lgkm waits for Pw RAW)
        f32x4 o[4] = {};
        f32x4 msum = {0.f, 0.f, 0.f, 0.f};
#pragma unroll
        for (int kti = 0; kti < 3; ++kti) {
            bf16x8 a = ldfrag(Pw + kti * 512 + rdoff);
#pragma unroll
            for (int nt = 0; nt < 4; ++nt) o[nt] = mfma16(a, vf[kti][nt], o[nt]);
            msum = mfma16(a, __builtin_bit_cast(bf16x8, bmask[kti]), msum);
        }
#pragma unroll
        for (int reg = 0; reg < 4; ++reg) {
            float rinv = 1.f / msum[reg];
            int row = bm * 256 + wm * 128 + rb * 16 + g * 4 + reg;
#pragma unroll
            for (int nt = 0; nt < 4; ++nt)
                qb[(size_t)row * 1024 + h * 64 + nt * 16 + lr] = f2b(o[nt][reg] * rinv);
        }
    }
}

// ---------------- outproj: out = attn @ WoT + bo ----------------
__global__ __launch_bounds__(512) void outproj_kernel(u16* __restrict__ ws, const float* __restrict__ bo,
                                                      float* __restrict__ out) {
    __shared__ u16 sm[2][2][2][8192];
    const u16* qb = ws + oQ / 2;
    const u16* WoT = ws + oWoT / 2;
    int tid = threadIdx.x;
    int lane = tid & 63;
    int w = tid >> 6, wm = w >> 2, wn = w & 3;
    int lr = lane & 15, lr2 = lr >> 1;
    const int rdoff = lr2 * 64 + (((((lane & 1) << 2) | (lane >> 4))) ^ lr2) * 8;
    int bid = blockIdx.x;
    int wg = (bid & 7) * 128 + (bid >> 3);
    int bm = wg >> 2, bn = wg & 3;

    const u16* aG = qb + (size_t)(bm * 256) * 1024;
    const u16* bG = WoT + (size_t)(bn * 256) * 1024;

    f32x4 acc[8][4] = {};
    GEMM_LOOP(aG, bG);

#pragma unroll
    for (int c = 0; c < 4; ++c) {
        int col = bn * 256 + wn * 64 + c * 16 + lr;
        float bias = bo[col];
#pragma unroll
        for (int r = 0; r < 8; ++r)
#pragma unroll
            for (int reg = 0; reg < 4; ++reg) {
                int row = bm * 256 + wm * 128 + r * 16 + (lane >> 4) * 4 + reg;
                out[(size_t)row * 1024 + col] = acc[r][c][reg] + bias;
            }
    }
}

extern "C" void kernel_launch(void* const* d_in, const int* in_sizes, int n_in,
                              void* d_out, int out_size, void* d_ws, size_t ws_size,
                              hipStream_t stream) {
    const float* x   = (const float*)d_in[0];
    const float* ctx = (const float*)d_in[1];
    const float* Wq  = (const float*)d_in[2];
    const float* Wk  = (const float*)d_in[3];
    const float* Wv  = (const float*)d_in[4];
    const float* Wo  = (const float*)d_in[5];
    const float* bo  = (const float*)d_in[6];
    float* out = (float*)d_out;
    u16* ws = (u16*)d_ws;
    u16* xb = (u16*)d_out;   // x as bf16, scratch in d_out (dead before outproj overwrites)
    (void)in_sizes; (void)n_in; (void)out_size; (void)ws_size;

    prep2_kernel<<<kXBlocks + 896 + 462 + 1408, 256, 0, stream>>>(Wq, Wk, Wv, Wo, ctx, x, ws, xb);
    kv_kernel<<<77 * 64, 64, 0, stream>>>(ws);
    qproj_attn_kernel<<<1024, 512, 0, stream>>>(xb, ws);
    outproj_kernel<<<1024, 512, 0, stream>>>(ws, bo, out);
}

// Round 13
// 500.698 us; speedup vs baseline: 1.1937x; 1.0011x over previous
//
#include <hip/hip_runtime.h>

typedef unsigned short u16;
typedef __bf16 bf16x8 __attribute__((ext_vector_type(8)));
typedef unsigned short u16x8 __attribute__((ext_vector_type(8)));
typedef float f32x4 __attribute__((ext_vector_type(4)));

// x: [16,4096,1024] f32, context: [16,77,768] f32
// Wq: [1024,1024], Wk/Wv: [768,1024], Wo: [1024,1024], bo: [1024]
// out: [16,4096,1024] f32
namespace {
constexpr int kB = 16;
constexpr int kHeads = 16, kDh = 64;
constexpr int kNcPadS = 80;
constexpr int kNcPadV = 96;

constexpr size_t oWqT = 0;                                         // [1024][1024] bf16 WqT[n][k]
constexpr size_t oWoT = oWqT + (size_t)1024 * 1024 * 2;
constexpr size_t oWkT = oWoT + (size_t)1024 * 1024 * 2;            // [1024][768]
constexpr size_t oWvT = oWkT + (size_t)1024 * 768 * 2;
constexpr size_t oCtx = oWvT + (size_t)1024 * 768 * 2;             // [1232][768]
constexpr size_t oKp  = oCtx + (size_t)1232 * 768 * 2;             // [16][16][80][64] (K/8)
constexpr size_t oVp  = oKp + (size_t)kB * kHeads * kNcPadS * kDh * 2; // [16][16][64][96] V^T
constexpr size_t oQ   = oVp + (size_t)kB * kHeads * kDh * kNcPadV * 2; // [65536][1024] bf16 (attn out)
constexpr int kXBlocks = 32768;   // x-convert blocks (16*4096*1024 / 8 / 256)
} // namespace

__device__ __forceinline__ u16 f2b(float f) {
    __bf16 h = (__bf16)f;
    return __builtin_bit_cast(u16, h);
}
__device__ __forceinline__ bf16x8 ldfrag(const u16* p) {
    return __builtin_bit_cast(bf16x8, *reinterpret_cast<const u16x8*>(p));
}
__device__ __forceinline__ f32x4 mfma16(bf16x8 a, bf16x8 b, f32x4 c) {
    return __builtin_amdgcn_mfma_f32_16x16x32_bf16(a, b, c, 0, 0, 0);
}
__device__ __forceinline__ void gload16(const u16* g, u16* lds) {
    __builtin_amdgcn_global_load_lds(
        (const __attribute__((address_space(1))) void*)g,
        (__attribute__((address_space(3))) void*)lds, 16, 0, 0);
}
__device__ __forceinline__ u16x8 pk8(float4 a, float4 b) {
    u16x8 p = { f2b(a.x), f2b(a.y), f2b(a.z), f2b(a.w),
                f2b(b.x), f2b(b.y), f2b(b.z), f2b(b.w) };
    return p;
}

#define VMCNT(N) asm volatile("s_waitcnt vmcnt(" #N ")" ::: "memory")
#define BARRIER  do { __builtin_amdgcn_s_barrier(); asm volatile("" ::: "memory"); } while (0)

// ---- pair-packed LDS unit: 256 logical rows x 32 k bf16 = 16KB, phys [128 pairs][8 slots][16B].
// logical (R,k): pr=R>>1, slot = ((R&1)*4 + (k>>3)) ^ (pr&7). Verified conflict-free+correct (rounds 3-11).
__device__ __forceinline__ void stage_u(const u16* gp, u16* unit, int tid, int kt) {
#pragma unroll
    for (int i = 0; i < 2; ++i) {
        int g = tid + i * 512;
        int prs = g >> 3;
        int s0 = (g & 7) ^ (prs & 7);
        gload16(gp + (size_t)(prs * 2 + (s0 >> 2)) * 1024 + kt + (s0 & 3) * 8,
                unit + ((g >> 6) << 9));
    }
}
// pp16: same packing for a [16 rows][32 k] 1KB sub-unit (u16 offset)
__device__ __forceinline__ int pp16(int row16, int k32) {
    return (row16 >> 1) * 64 + (((((row16 & 1) << 2) | (k32 >> 3)) ^ ((row16 >> 1) & 7)) * 8) + (k32 & 7);
}

// ---------------- prep: x->bf16 (bulk) + weight transposes + ctx convert + K/V pad zero (one grid) ----
__global__ __launch_bounds__(256) void prep2_kernel(
    const float* __restrict__ Wq, const float* __restrict__ Wk,
    const float* __restrict__ Wv, const float* __restrict__ Wo,
    const float* __restrict__ ctx, const float* __restrict__ x,
    u16* __restrict__ ws, u16* __restrict__ xb) {
    __shared__ u16 tl[64][72];
    int b = blockIdx.x;
    int tid = threadIdx.x;
    if (b < kXBlocks) {   // x fp32 -> bf16 into d_out scratch (8 elems/thread)
        size_t i = (size_t)b * 256 + tid;
        const float4* s = reinterpret_cast<const float4*>(x) + 2 * i;
        float4 v0 = s[0], v1 = s[1];
        *reinterpret_cast<u16x8*>(xb + 8 * i) = pk8(v0, v1);
        return;
    }
    b -= kXBlocks;
    if (b < 896) {
        const float* S; u16* D; int t, DC;
        if (b < 256)       { S = Wq; D = ws + oWqT / 2; t = b;       DC = 1024; }
        else if (b < 512)  { S = Wo; D = ws + oWoT / 2; t = b - 256; DC = 1024; }
        else if (b < 704)  { S = Wk; D = ws + oWkT / 2; t = b - 512; DC = 768;  }
        else               { S = Wv; D = ws + oWvT / 2; t = b - 704; DC = 768;  }
        int tk = t >> 4, tn = t & 15;
        int k0 = tk * 64, n0 = tn * 64;
#pragma unroll
        for (int i = 0; i < 4; ++i) {
            int r = (tid >> 4) + i * 16;
            float4 v = *reinterpret_cast<const float4*>(S + (size_t)(k0 + r) * 1024 + n0 + (tid & 15) * 4);
            u16 e0 = f2b(v.x), e1 = f2b(v.y), e2 = f2b(v.z), e3 = f2b(v.w);
            u16* p = &tl[r][(tid & 15) * 4];
            p[0] = e0; p[1] = e1; p[2] = e2; p[3] = e3;
        }
        __syncthreads();
#pragma unroll
        for (int i = 0; i < 2; ++i) {
            int n = (tid >> 3) + i * 32;
            u16x8 o;
#pragma unroll
            for (int j = 0; j < 8; ++j) o[j] = tl[(tid & 7) * 8 + j][n];
            *reinterpret_cast<u16x8*>(D + (size_t)(n0 + n) * DC + k0 + (tid & 7) * 8) = o;
        }
        return;
    }
    if (b < 896 + 462) {
        size_t i = (size_t)(b - 896) * 2048 + tid * 8;
        const float4* s = reinterpret_cast<const float4*>(ctx) + i / 4;
        float4 v0 = s[0], v1 = s[1];
        *reinterpret_cast<u16x8*>(ws + oCtx / 2 + i) = pk8(v0, v1);
        return;
    }
    size_t j = (size_t)(b - 896 - 462) * 2048 + tid * 8;
    u16x8 z = {0, 0, 0, 0, 0, 0, 0, 0};
    *reinterpret_cast<u16x8*>(ws + oKp / 2 + j) = z;
}

// ---------------- KV projection ----------------
__global__ __launch_bounds__(64) void kv_kernel(u16* __restrict__ ws) {
    const u16* ctxb = ws + oCtx / 2;
    const u16* WkT = ws + oWkT / 2;
    const u16* WvT = ws + oWvT / 2;
    u16* Kp = ws + oKp / 2;
    u16* Vp = ws + oVp / 2;
    int l = threadIdx.x;
    int mt = blockIdx.x >> 6;
    int nt = blockIdx.x & 63;
    int rowA = mt * 16 + (l & 15);
    int rowB = nt * 16 + (l & 15);
    int koff = (l >> 4) * 8;
    f32x4 accK = {0.f, 0.f, 0.f, 0.f}, accV = {0.f, 0.f, 0.f, 0.f};
    for (int k = 0; k < 768; k += 32) {
        bf16x8 a  = ldfrag(ctxb + rowA * 768 + k + koff);
        bf16x8 bk = ldfrag(WkT + rowB * 768 + k + koff);
        bf16x8 bv = ldfrag(WvT + rowB * 768 + k + koff);
        accK = mfma16(a, bk, accK);
        accV = mfma16(a, bv, accV);
    }
    int c = nt * 16 + (l & 15);
    int h = c >> 6, d = c & 63;
#pragma unroll
    for (int r = 0; r < 4; ++r) {
        int row = mt * 16 + (l >> 4) * 4 + r;
        int b = row / 77, j = row - b * 77;
        Kp[((size_t)(b * 16 + h) * kNcPadS + j) * kDh + d] = f2b(accK[r] * 0.125f);
        Vp[((size_t)(b * 16 + h) * kDh + d) * kNcPadV + j] = f2b(accV[r]);
    }
}

// ---------------- m201-style 4-phase K-tile GEMM schedule (verified rounds 6-11) ----------------
#define GPHASE(RLO, KS, READB, STAGE, VM) do {                                  \
    if (READB) { _Pragma("unroll") for (int c = 0; c < 4; ++c)                  \
        fb[c] = ldfrag(bU##KS + (wn * 4 + c) * 512 + rdoff); }                  \
    _Pragma("unroll") for (int r = 0; r < 4; ++r)                               \
        fa[r] = ldfrag(aU##KS + (wm * 8 + (RLO) + r) * 512 + rdoff);            \
    STAGE;                                                                      \
    BARRIER;                                                                    \
    __builtin_amdgcn_s_setprio(1);                                              \
    _Pragma("unroll") for (int r = 0; r < 4; ++r)                               \
        _Pragma("unroll") for (int c = 0; c < 4; ++c)                           \
            acc[(RLO) + r][c] = mfma16(fa[r], fb[c], acc[(RLO) + r][c]);        \
    __builtin_amdgcn_s_setprio(0);                                              \
    VM;                                                                         \
    BARRIER;                                                                    \
} while (0)

#define GEMM_LOOP(aGp, bGp)                                                                          \
    stage_u(aGp, &sm[0][0][0][0], tid, 0);                                                           \
    stage_u(bGp, &sm[1][0][0][0], tid, 0);                                                           \
    stage_u(aGp, &sm[0][0][1][0], tid, 32);                                                          \
    stage_u(bGp, &sm[1][0][1][0], tid, 32);                                                          \
    stage_u(aGp, &sm[0][1][0][0], tid, 64);                                                          \
    stage_u(bGp, &sm[1][1][0][0], tid, 64);                                                          \
    VMCNT(8); BARRIER;                                                                               \
    for (int t = 0; t < 16; ++t) {                                                                   \
        const int d = t & 1, e = d ^ 1;                                                              \
        const u16* aU0 = &sm[0][d][0][0];                                                            \
        const u16* aU1 = &sm[0][d][1][0];                                                            \
        const u16* bU0 = &sm[1][d][0][0];                                                            \
        const u16* bU1 = &sm[1][d][1][0];                                                            \
        bf16x8 fa[4], fb[4];                                                                         \
        GPHASE(0, 0, true,  { if (t < 15) stage_u(aGp, &sm[0][e][1][0], tid, (t + 1) * 64 + 32); },  \
               {});                                                                                  \
        GPHASE(4, 0, false, { if (t < 15) stage_u(bGp, &sm[1][e][1][0], tid, (t + 1) * 64 + 32); },  \
               { if (t < 15) { VMCNT(8); } else { VMCNT(0); } });                                    \
        GPHASE(0, 1, true,  { if (t < 14) stage_u(aGp, &sm[0][d][0][0], tid, (t + 2) * 64); },       \
               {});                                                                                  \
        GPHASE(4, 1, false, { if (t < 14) stage_u(bGp, &sm[1][d][0][0], tid, (t + 2) * 64); },       \
               { if (t < 14) { VMCNT(8); } else if (t == 14) { VMCNT(4); } });                       \
    }

// ---------------- qproj+attn fused: q = xb @ WqT, then per-wave attention, write attn-out ----------------
__global__ __launch_bounds__(512) void qproj_attn_kernel(const u16* __restrict__ xb, u16* __restrict__ ws) {
    __shared__ u16 sm[2][2][2][8192];   // 128 KiB GEMM buffers; reused as q store after the loop
    __shared__ u16 Pb[8][1536];         // per-wave P tile: 3 pp16 units of [16][32] (24 KiB)
    const u16* WqT = ws + oWqT / 2;
    u16* qb = ws + oQ / 2;
    int tid = threadIdx.x;
    int lane = tid & 63;
    int w = tid >> 6, wm = w >> 2, wn = w & 3;
    int lr = lane & 15, lr2 = lr >> 1;
    const int rdoff = lr2 * 64 + (((((lane & 1) << 2) | (lane >> 4))) ^ lr2) * 8;
    int bid = blockIdx.x;
    int wg = (bid & 7) * 128 + (bid >> 3);   // XCD swizzle (1024 % 8 == 0, bijective)
    int bm = wg >> 2, bn = wg & 3;

    const u16* aG = xb + (size_t)(bm * 256) * 1024;
    const u16* bG = WqT + (size_t)(bn * 256) * 1024;

    f32x4 acc[8][4] = {};
    GEMM_LOOP(aG, bG);

    // ---- fused attention epilogue (verified rounds 8-11) ----
    u16* smf = &sm[0][0][0][0];
    u16* qw = smf + (size_t)w * 8192;   // wave-private 16 KB: 16 units [16 rows][32 k] pp16
    u16* Pw = &Pb[w][0];
    int g = lane >> 4, g8 = g * 8;

    // write q tile bf16 to LDS (unit = r*2 + (d>>5); frees acc)
#pragma unroll
    for (int r = 0; r < 8; ++r)
#pragma unroll
        for (int c = 0; c < 4; ++c) {
            int dd = c * 16 + lr;
            int unit = r * 2 + (dd >> 5);
            int k32 = dd & 31;
#pragma unroll
            for (int reg = 0; reg < 4; ++reg)
                qw[unit * 512 + pp16(g * 4 + reg, k32)] = f2b(acc[r][c][reg]);
        }
    // zero P unit 2 (cols 64..95; 64..79 rewritten per row-block before each read)
    {
        u16x8 z = {0, 0, 0, 0, 0, 0, 0, 0};
        *reinterpret_cast<u16x8*>(Pw + 2 * 512 + lane * 8) = z;
    }
    // hoist K/V fragments from global (L2-resident; K pre-scaled by 1/8, pads zeroed)
    int b = bm >> 4;
    int h = bn * 4 + wn;
    const u16* Kh = ws + oKp / 2 + (size_t)(b * 16 + h) * kNcPadS * kDh;
    const u16* Vh = ws + oVp / 2 + (size_t)(b * 16 + h) * kDh * kNcPadV;
    bf16x8 kf[5][2], vf[3][4];
#pragma unroll
    for (int nt = 0; nt < 5; ++nt)
#pragma unroll
        for (int kc = 0; kc < 2; ++kc)
            kf[nt][kc] = ldfrag(Kh + (nt * 16 + lr) * 64 + kc * 32 + g8);
#pragma unroll
    for (int kti = 0; kti < 3; ++kti)
#pragma unroll
        for (int nt = 0; nt < 4; ++nt)
            vf[kti][nt] = ldfrag(Vh + (nt * 16 + lr) * kNcPadV + kti * 32 + g8);
    u16x8 bmask[3];
#pragma unroll
    for (int kti = 0; kti < 3; ++kti)
#pragma unroll
        for (int j = 0; j < 8; ++j)
            bmask[kti][j] = (kti * 32 + g8 + j < 77) ? (u16)0x3F80 : (u16)0;

#pragma unroll 1
    for (int rb = 0; rb < 8; ++rb) {
        // scores (no max-subtraction: s~N(0,1), softmax shift-invariant — verified rounds 7-11)
        f32x4 s[5] = {};
#pragma unroll
        for (int kc = 0; kc < 2; ++kc) {
            bf16x8 a = ldfrag(qw + (rb * 2 + kc) * 512 + rdoff);
#pragma unroll
            for (int nt = 0; nt < 5; ++nt) s[nt] = mfma16(a, kf[nt][kc], s[nt]);
        }
        // P = exp(s) -> wave-private pp16 tile
#pragma unroll
        for (int nt = 0; nt < 5; ++nt)
#pragma unroll
            for (int reg = 0; reg < 4; ++reg) {
                int j = nt * 16 + lr;
                Pw[(j >> 5) * 512 + pp16(g * 4 + reg, j & 31)] = f2b(__expf(s[nt][reg]));
            }
        // PV + masked-ones row-sum via MFMA (compiler inserts the lgkm waits for Pw RAW)
        f32x4 o[4] = {};
        f32x4 msum = {0.f, 0.f, 0.f, 0.f};
#pragma unroll
        for (int kti = 0; kti < 3; ++kti) {
            bf16x8 a = ldfrag(Pw + kti * 512 + rdoff);
#pragma unroll
            for (int nt = 0; nt < 4; ++nt) o[nt] = mfma16(a, vf[kti][nt], o[nt]);
            msum = mfma16(a, __builtin_bit_cast(bf16x8, bmask[kti]), msum);
        }
#pragma unroll
        for (int reg = 0; reg < 4; ++reg) {
            float rinv = 1.f / msum[reg];
            int row = bm * 256 + wm * 128 + rb * 16 + g * 4 + reg;
#pragma unroll
            for (int nt = 0; nt < 4; ++nt)
                qb[(size_t)row * 1024 + h * 64 + nt * 16 + lr] = f2b(o[nt][reg] * rinv);
        }
    }
}

// ---------------- outproj: out = attn @ WoT + bo ----------------
__global__ __launch_bounds__(512) void outproj_kernel(u16* __restrict__ ws, const float* __restrict__ bo,
                                                      float* __restrict__ out) {
    __shared__ u16 sm[2][2][2][8192];
    const u16* qb = ws + oQ / 2;
    const u16* WoT = ws + oWoT / 2;
    int tid = threadIdx.x;
    int lane = tid & 63;
    int w = tid >> 6, wm = w >> 2, wn = w & 3;
    int lr = lane & 15, lr2 = lr >> 1;
    const int rdoff = lr2 * 64 + (((((lane & 1) << 2) | (lane >> 4))) ^ lr2) * 8;
    int bid = blockIdx.x;
    int wg = (bid & 7) * 128 + (bid >> 3);
    int bm = wg >> 2, bn = wg & 3;

    const u16* aG = qb + (size_t)(bm * 256) * 1024;
    const u16* bG = WoT + (size_t)(bn * 256) * 1024;

    f32x4 acc[8][4] = {};
    GEMM_LOOP(aG, bG);

#pragma unroll
    for (int c = 0; c < 4; ++c) {
        int col = bn * 256 + wn * 64 + c * 16 + lr;
        float bias = bo[col];
#pragma unroll
        for (int r = 0; r < 8; ++r)
#pragma unroll
            for (int reg = 0; reg < 4; ++reg) {
                int row = bm * 256 + wm * 128 + r * 16 + (lane >> 4) * 4 + reg;
                out[(size_t)row * 1024 + col] = acc[r][c][reg] + bias;
            }
    }
}

extern "C" void kernel_launch(void* const* d_in, const int* in_sizes, int n_in,
                              void* d_out, int out_size, void* d_ws, size_t ws_size,
                              hipStream_t stream) {
    const float* x   = (const float*)d_in[0];
    const float* ctx = (const float*)d_in[1];
    const float* Wq  = (const float*)d_in[2];
    const float* Wk  = (const float*)d_in[3];
    const float* Wv  = (const float*)d_in[4];
    const float* Wo  = (const float*)d_in[5];
    const float* bo  = (const float*)d_in[6];
    float* out = (float*)d_out;
    u16* ws = (u16*)d_ws;
    u16* xb = (u16*)d_out;   // x as bf16, scratch in d_out (dead before outproj overwrites)
    (void)in_sizes; (void)n_in; (void)out_size; (void)ws_size;

    prep2_kernel<<<kXBlocks + 896 + 462 + 1408, 256, 0, stream>>>(Wq, Wk, Wv, Wo, ctx, x, ws, xb);
    kv_kernel<<<77 * 64, 64, 0, stream>>>(ws);
    qproj_attn_kernel<<<1024, 512, 0, stream>>>(xb, ws);
    outproj_kernel<<<1024, 512, 0, stream>>>(ws, bo, out);
}